// Round 19
// baseline (140.066 us; speedup 1.0000x reference)
//
#include <hip/hip_runtime.h>
#include <hip/hip_fp16.h>

#define ND      10000
#define NDIS    10000
#define E_EDGES 400000
#define E4N     (E_EDGES / 4)
#define DIM     128
#define D2      256   // 2*DIM
#define H1      256   // d4/2
#define H2      128   // d4/4
#define EPSBN   1e-5f
#define GJ      16    // diseases per group (16-row MFMA tiles, no padding)
#define NGRP16  (NDIS / GJ)   // 625
#define WSGRID  512
#define NCOPY   32    // privatized histogram copies
#define ELLS    128   // ELL row stride (max degree bound; Poisson(40) -> safe)
#define LDAH    136   // padded LDS row stride (halves) for aggz1's MFMA A-tile
#define LDXH    264   // padded LDS row stride (halves) for z2w's MFMA A-tile
// zero region: NCOPY*(ND+NDIS) ints + 768 stat floats
#define ZERO_N4 ((NCOPY * (ND + NDIS) + 768) / 4)
#define ZBLK    ((ZERO_N4 + 255) / 256)
#define W2B     (D2 * H2 / 256)               // 128 W2->fp16 blocks in k_pre
#define FILLB   ((E_EDGES / 4 + 255) / 256)   // 391 edge blocks in k_fill
#define HNB     (ND * 32 / 256)               // 1250 hn-conversion blocks in k_fill

typedef _Float16 f16x8 __attribute__((ext_vector_type(8)));
typedef float    f32x4 __attribute__((ext_vector_type(4)));

// ------- fused: zero histograms/stats + M1h (fp16) / c1 precompute + W2->fp16 ------------
__global__ void k_pre(int4* __restrict__ zp,
                      const float* __restrict__ Wg, const float* __restrict__ W1,
                      const float* __restrict__ b_gcn, const float* __restrict__ b1,
                      const float* __restrict__ W2,
                      __half* __restrict__ M1h, float* __restrict__ c1,
                      __half* __restrict__ W2h) {
    int b = blockIdx.x;
    int t = threadIdx.x;
    if (b < ZBLK) {
        int i = b * 256 + t;
        if (i < ZERO_N4) zp[i] = make_int4(0, 0, 0, 0);
        return;
    }
    int r = b - ZBLK;          // 0..128+W2B
    if (r < DIM) {             // M1[r][t] = sum_c Wg[r][c] * W1[256+c][t]  -> fp16
        float acc = 0.f;
        #pragma unroll 8
        for (int c = 0; c < D2; ++c)
            acc += Wg[r * D2 + c] * W1[(D2 + c) * H1 + t];
        M1h[r * H1 + t] = __float2half_rn(acc);
    } else if (r == DIM) {     // c1[t]
        float acc = b1[t];
        #pragma unroll 4
        for (int i = 0; i < D2; ++i)
            acc += b_gcn[i] * (W1[i * H1 + t] + W1[(D2 + i) * H1 + t]);
        c1[t] = acc;
    } else {                   // W2 -> fp16
        int i = (r - DIM - 1) * 256 + t;
        W2h[i] = __float2half_rn(W2[i]);
    }
}

// ---------------- degree counting, 32-way privatized; dst-atomic returns edge rank -------
__global__ void k_degrees(const int* __restrict__ src, const int* __restrict__ dst,
                          int* __restrict__ cnts, int* __restrict__ cntd,
                          int* __restrict__ rank) {
    int e4 = blockIdx.x * blockDim.x + threadIdx.x;
    if (e4 >= E4N) return;
    int c = blockIdx.x & (NCOPY - 1);
    int4 sv = ((const int4*)src)[e4];
    int4 dv = ((const int4*)dst)[e4];
    atomicAdd(&cnts[c * ND + sv.x], 1);
    atomicAdd(&cnts[c * ND + sv.y], 1);
    atomicAdd(&cnts[c * ND + sv.z], 1);
    atomicAdd(&cnts[c * ND + sv.w], 1);
    int4 rv;
    rv.x = atomicAdd(&cntd[c * NDIS + dv.x], 1);
    rv.y = atomicAdd(&cntd[c * NDIS + dv.y], 1);
    rv.z = atomicAdd(&cntd[c * NDIS + dv.z], 1);
    rv.w = atomicAdd(&cntd[c * NDIS + dv.w], 1);
    ((int4*)rank)[e4] = rv;
}

// ------- reduce copies: totals, in-place per-copy exclusive prefix, norm_out -------------
__global__ void k_red(int* __restrict__ cnts, int* __restrict__ cntd,
                      int* __restrict__ cnt_dst, float* __restrict__ norm_out) {
    int d = blockIdx.x * blockDim.x + threadIdx.x;
    if (d >= NDIS) return;
    int s = 0;
    #pragma unroll
    for (int c = 0; c < NCOPY; ++c) {
        int v = cntd[c * NDIS + d];
        cntd[c * NDIS + d] = s;       // overwrite with exclusive prefix (copyoff)
        s += v;
    }
    cnt_dst[d] = s;
    int s2 = 0;
    #pragma unroll
    for (int c = 0; c < NCOPY; ++c) s2 += cnts[c * ND + d];
    norm_out[d] = rsqrtf(fmaxf((float)s2, 1.f));
}

// ------- ELL fill (atomic-free) + hn = fp16(norm_out * h_drug) pre-scale ----------------
__global__ void k_fill(const int* __restrict__ src, const int* __restrict__ dst,
                       const int* __restrict__ rank, const int* __restrict__ copyoff,
                       int* __restrict__ ell_src,
                       const float* __restrict__ norm_out, const float* __restrict__ h_drug,
                       __half* __restrict__ hn) {
    int b = blockIdx.x;
    if (b >= FILLB) {   // hn conversion: 8 rows per block, lane covers 4 cols (8B store)
        int row = (b - FILLB) * 8 + (threadIdx.x >> 5);
        int L = threadIdx.x & 31;
        float no = norm_out[row];
        float4 v = *(const float4*)&h_drug[(size_t)row * DIM + L * 4];
        __half2 h01 = __halves2half2(__float2half_rn(v.x * no), __float2half_rn(v.y * no));
        __half2 h23 = __halves2half2(__float2half_rn(v.z * no), __float2half_rn(v.w * no));
        uint2 u;
        u.x = *(unsigned int*)&h01;
        u.y = *(unsigned int*)&h23;
        *(uint2*)&hn[(size_t)row * DIM + L * 4] = u;
        return;
    }
    int e4 = b * blockDim.x + threadIdx.x;
    if (e4 >= E4N) return;
    int c = b & (NCOPY - 1);          // must match k_degrees' mapping
    int4 sv = ((const int4*)src)[e4];
    int4 dv = ((const int4*)dst)[e4];
    int4 rv = ((const int4*)rank)[e4];
    int ix = copyoff[c * NDIS + dv.x] + rv.x;
    int iy = copyoff[c * NDIS + dv.y] + rv.y;
    int iz = copyoff[c * NDIS + dv.z] + rv.z;
    int iw = copyoff[c * NDIS + dv.w] + rv.w;
    if (ix < ELLS) ell_src[(dv.x << 7) + ix] = sv.x;
    if (iy < ELLS) ell_src[(dv.y << 7) + iy] = sv.y;
    if (iz < ELLS) ell_src[(dv.z << 7) + iz] = sv.z;
    if (iw < ELLS) ell_src[(dv.w << 7) + iw] = sv.w;
}

// ===== FUSED aggregation + MFMA Z1 GEMM + weighted BN1 stats  (16 real rows/group) =====
// Wave wid aggregates diseases jb+wid (row wid) and jb+wid+8 (row wid+8).
// Edge IDs via proven uniform ell_src loads (NO cross-lane ops in divergent guards).
__global__ __launch_bounds__(512) void k_aggz1(
        const int* __restrict__ ell_src, const int* __restrict__ cnt_dst,
        const __half* __restrict__ hn, const __half* __restrict__ M1h,
        const float* __restrict__ c1,
        float* __restrict__ Z1, float* __restrict__ sum1, float* __restrict__ sumsq1) {
    __shared__ __half sA[16][LDAH];        // 4352 B
    int tid = threadIdx.x;
    int wid = tid >> 6;                    // 0..7
    int lane = tid & 63;
    int hf = lane >> 5, L = lane & 31;     // phase-A roles
    int l15 = lane & 15, lg = lane >> 4;   // MFMA roles

    const _Float16* M1f = (const _Float16*)M1h;
    int c0a = 32 * wid + l15;
    int c0b = c0a + 16;
    f16x8 bfr[2][4];
    #pragma unroll
    for (int t = 0; t < 2; ++t) {
        int cc = t ? c0b : c0a;
        #pragma unroll
        for (int kk = 0; kk < 4; ++kk) {
            f16x8 f;
            #pragma unroll
            for (int j = 0; j < 4; ++j) {
                f[j]     = M1f[(kk * 32 + 4 * lg + j) * H1 + cc];
                f[j + 4] = M1f[(kk * 32 + 16 + 4 * lg + j) * H1 + cc];
            }
            bfr[t][kk] = f;
        }
    }
    float c1a = c1[c0a], c1b = c1[c0b];
    float psA = 0.f, pqA = 0.f, psB = 0.f, pqB = 0.f;

    for (int grp = blockIdx.x; grp < NGRP16; grp += gridDim.x) {
        int jb = grp * GJ;
        // ---- phase A: gather diseases jb+wid, jb+wid+8 -> sA rows wid, wid+8 ----
        {
            int j0 = jb + wid, j1 = j0 + 8;
            int n0t = cnt_dst[j0], n1t = cnt_dst[j1];     // true counts (for norm)
            int n0 = n0t < ELLS ? n0t : ELLS;
            int n1 = n1t < ELLS ? n1t : ELLS;
            int beg0 = j0 << 7, beg1 = j1 << 7;
            float4 a0 = make_float4(0.f, 0.f, 0.f, 0.f);
            float4 a1 = a0, a2 = a0, a3 = a0;
            int nmx = n0 > n1 ? n0 : n1;
            for (int i = hf; i < nmx; i += 4) {   // 4 chains: (d0,d0+2,d1,d1+2)
                int i2 = i + 2;
                if (i < n0) {
                    int s = ell_src[beg0 + i];
                    uint2 u = *(const uint2*)&hn[(size_t)s * DIM + L * 4];
                    float2 p = __half22float2(*(__half2*)&u.x);
                    float2 q = __half22float2(*(__half2*)&u.y);
                    a0.x += p.x; a0.y += p.y; a0.z += q.x; a0.w += q.y;
                }
                if (i2 < n0) {
                    int s = ell_src[beg0 + i2];
                    uint2 u = *(const uint2*)&hn[(size_t)s * DIM + L * 4];
                    float2 p = __half22float2(*(__half2*)&u.x);
                    float2 q = __half22float2(*(__half2*)&u.y);
                    a1.x += p.x; a1.y += p.y; a1.z += q.x; a1.w += q.y;
                }
                if (i < n1) {
                    int s = ell_src[beg1 + i];
                    uint2 u = *(const uint2*)&hn[(size_t)s * DIM + L * 4];
                    float2 p = __half22float2(*(__half2*)&u.x);
                    float2 q = __half22float2(*(__half2*)&u.y);
                    a2.x += p.x; a2.y += p.y; a2.z += q.x; a2.w += q.y;
                }
                if (i2 < n1) {
                    int s = ell_src[beg1 + i2];
                    uint2 u = *(const uint2*)&hn[(size_t)s * DIM + L * 4];
                    float2 p = __half22float2(*(__half2*)&u.x);
                    float2 q = __half22float2(*(__half2*)&u.y);
                    a3.x += p.x; a3.y += p.y; a3.z += q.x; a3.w += q.y;
                }
            }
            a0.x += a1.x; a0.y += a1.y; a0.z += a1.z; a0.w += a1.w;
            a2.x += a3.x; a2.y += a3.y; a2.z += a3.z; a2.w += a3.w;
            a0.x += __shfl_down(a0.x, 32, 64);
            a0.y += __shfl_down(a0.y, 32, 64);
            a0.z += __shfl_down(a0.z, 32, 64);
            a0.w += __shfl_down(a0.w, 32, 64);
            a2.x += __shfl_down(a2.x, 32, 64);
            a2.y += __shfl_down(a2.y, 32, 64);
            a2.z += __shfl_down(a2.z, 32, 64);
            a2.w += __shfl_down(a2.w, 32, 64);
            if (hf == 0) {
                float ni0 = rsqrtf(fmaxf((float)n0t, 1.f));
                float ni1 = rsqrtf(fmaxf((float)n1t, 1.f));
                __half2 h01 = __halves2half2(__float2half_rn(a0.x * ni0),
                                             __float2half_rn(a0.y * ni0));
                __half2 h23 = __halves2half2(__float2half_rn(a0.z * ni0),
                                             __float2half_rn(a0.w * ni0));
                uint2 u;
                u.x = *(unsigned int*)&h01;
                u.y = *(unsigned int*)&h23;
                *(uint2*)&sA[wid][L * 4] = u;
                h01 = __halves2half2(__float2half_rn(a2.x * ni1),
                                     __float2half_rn(a2.y * ni1));
                h23 = __halves2half2(__float2half_rn(a2.z * ni1),
                                     __float2half_rn(a2.w * ni1));
                u.x = *(unsigned int*)&h01;
                u.y = *(unsigned int*)&h23;
                *(uint2*)&sA[wid + 8][L * 4] = u;
            }
        }
        __syncthreads();
        // ---- phase B: MFMA.  D[16x256] = A[16x128] @ M1h ; all 16 rows real ----
        {
            f32x4 cA = {0.f, 0.f, 0.f, 0.f};
            f32x4 cB = {0.f, 0.f, 0.f, 0.f};
            const _Float16* arow = (const _Float16*)&sA[l15][0];
            #pragma unroll
            for (int kk = 0; kk < 4; ++kk) {
                uint2 lo = *(const uint2*)&arow[kk * 32 + 4 * lg];
                uint2 hi = *(const uint2*)&arow[kk * 32 + 16 + 4 * lg];
                f16x8 af;
                ((uint2*)&af)[0] = lo;
                ((uint2*)&af)[1] = hi;
                cA = __builtin_amdgcn_mfma_f32_16x16x32_f16(af, bfr[0][kk], cA, 0, 0, 0);
                cB = __builtin_amdgcn_mfma_f32_16x16x32_f16(af, bfr[1][kk], cB, 0, 0, 0);
            }
            int row0 = lg * 4;             // rows 0..15, all real
            #pragma unroll
            for (int reg = 0; reg < 4; ++reg) {
                int row = row0 + reg;
                float w = (float)cnt_dst[jb + row];
                float za = cA[reg] + c1a;
                float zb = cB[reg] + c1b;
                Z1[(size_t)(jb + row) * H1 + c0a] = za;
                Z1[(size_t)(jb + row) * H1 + c0b] = zb;
                psA += w * za; pqA += w * za * za;
                psB += w * zb; pqB += w * zb * zb;
            }
        }
        __syncthreads();
    }
    // fold stats over all 4 lane groups (16 rows)
    psA += __shfl_down(psA, 32, 64); psA += __shfl_down(psA, 16, 64);
    pqA += __shfl_down(pqA, 32, 64); pqA += __shfl_down(pqA, 16, 64);
    psB += __shfl_down(psB, 32, 64); psB += __shfl_down(psB, 16, 64);
    pqB += __shfl_down(pqB, 32, 64); pqB += __shfl_down(pqB, 16, 64);
    if (lane < 16) {
        atomicAdd(&sum1[32 * wid + lane], psA);
        atomicAdd(&sumsq1[32 * wid + lane], pqA);
        atomicAdd(&sum1[32 * wid + 16 + lane], psB);
        atomicAdd(&sumsq1[32 * wid + 16 + lane], pqB);
    }
}

// ===== Z2 = relu(bn1(Z1)) @ W2 + b2 ; BN2 stats — MFMA, 16 real rows/group =====
__global__ __launch_bounds__(512) void k_z2w(
        const float* __restrict__ Z1, const int* __restrict__ cnt_dst,
        const float* __restrict__ sum1, const float* __restrict__ sumsq1,
        const float* __restrict__ gamma1, const float* __restrict__ beta1,
        const __half* __restrict__ W2h, const float* __restrict__ b2,
        float* __restrict__ Z2, float* __restrict__ sum2, float* __restrict__ sumsq2) {
    __shared__ __half sX[16][LDXH];        // 8448 B
    __shared__ float sc1[H1], sh1[H1];     // 2 KB
    int tid = threadIdx.x;
    int wid = tid >> 6;
    int lane = tid & 63;
    int l15 = lane & 15, lg = lane >> 4;

    const _Float16* W2f = (const _Float16*)W2h;
    int cc = 16 * wid + l15;               // this lane's output column
    f16x8 bfr[8];
    #pragma unroll
    for (int kk = 0; kk < 8; ++kk) {
        f16x8 f;
        #pragma unroll
        for (int j = 0; j < 4; ++j) {
            f[j]     = W2f[(kk * 32 + 4 * lg + j) * H2 + cc];
            f[j + 4] = W2f[(kk * 32 + 16 + 4 * lg + j) * H2 + cc];
        }
        bfr[kk] = f;
    }
    if (tid < H1) {   // inline BN1 finalize
        float mn = sum1[tid] * (1.f / E_EDGES);
        float vv = sumsq1[tid] * (1.f / E_EDGES) - mn * mn;
        float s = rsqrtf(vv + EPSBN) * gamma1[tid];
        sc1[tid] = s;
        sh1[tid] = beta1[tid] - mn * s;
    }
    float b2c = b2[cc];
    float ps = 0.f, pq = 0.f;
    __syncthreads();
    for (int grp = blockIdx.x; grp < NGRP16; grp += gridDim.x) {
        int jb = grp * GJ;
        {   // stage 16 rows = fp16 relu(bn1(Z1[jb..jb+15]))  (512 thr x 2 float4)
            #pragma unroll
            for (int xx = 0; xx < 2; ++xx) {
                int x = tid + xx * 512;
                int g = x >> 6;
                int c = (x * 4) & (H1 - 1);
                float4 v = ((const float4*)(Z1 + (size_t)jb * H1))[x];
                v.x = fmaxf(v.x * sc1[c]     + sh1[c],     0.f);
                v.y = fmaxf(v.y * sc1[c + 1] + sh1[c + 1], 0.f);
                v.z = fmaxf(v.z * sc1[c + 2] + sh1[c + 2], 0.f);
                v.w = fmaxf(v.w * sc1[c + 3] + sh1[c + 3], 0.f);
                __half2 h01 = __halves2half2(__float2half_rn(v.x), __float2half_rn(v.y));
                __half2 h23 = __halves2half2(__float2half_rn(v.z), __float2half_rn(v.w));
                uint2 u;
                u.x = *(unsigned int*)&h01;
                u.y = *(unsigned int*)&h23;
                *(uint2*)&sX[g][c] = u;
            }
        }
        __syncthreads();
        {   // MFMA: D[16x128] = X[16x256] @ W2h ; all 16 rows real
            f32x4 cacc = {0.f, 0.f, 0.f, 0.f};
            const _Float16* arow = (const _Float16*)&sX[l15][0];
            #pragma unroll
            for (int kk = 0; kk < 8; ++kk) {
                uint2 lo = *(const uint2*)&arow[kk * 32 + 4 * lg];
                uint2 hi = *(const uint2*)&arow[kk * 32 + 16 + 4 * lg];
                f16x8 af;
                ((uint2*)&af)[0] = lo;
                ((uint2*)&af)[1] = hi;
                cacc = __builtin_amdgcn_mfma_f32_16x16x32_f16(af, bfr[kk], cacc, 0, 0, 0);
            }
            int row0 = lg * 4;
            #pragma unroll
            for (int reg = 0; reg < 4; ++reg) {
                int row = row0 + reg;
                float w = (float)cnt_dst[jb + row];
                float z = cacc[reg] + b2c;
                Z2[(size_t)(jb + row) * H2 + cc] = z;
                ps += w * z;
                pq += w * z * z;
            }
        }
        __syncthreads();
    }
    ps += __shfl_down(ps, 32, 64); ps += __shfl_down(ps, 16, 64);
    pq += __shfl_down(pq, 32, 64); pq += __shfl_down(pq, 16, 64);
    if (lane < 16) {
        atomicAdd(&sum2[cc], ps);
        atomicAdd(&sumsq2[cc], pq);
    }
}

// ------- S[j] = sigmoid( relu(bn2(Z2[j])) @ W3 + b3 )  (BN2 hoisted, grid-stride) --------
__global__ void k_score(const float* __restrict__ Z2,
                        const float* __restrict__ sum2, const float* __restrict__ sumsq2,
                        const float* __restrict__ gamma2, const float* __restrict__ beta2,
                        const float* __restrict__ W3, const float* __restrict__ b3,
                        float* __restrict__ S) {
    int lane = threadIdx.x & 63;
    int gw = (blockIdx.x * blockDim.x + threadIdx.x) >> 6;
    int nw = (gridDim.x * blockDim.x) >> 6;
    int k0 = lane, k1 = lane + 64;
    float m0 = sum2[k0] * (1.f / E_EDGES);
    float v0 = sumsq2[k0] * (1.f / E_EDGES) - m0 * m0;
    float s0 = rsqrtf(v0 + EPSBN) * gamma2[k0];
    float h0 = beta2[k0] - m0 * s0;
    float w30 = W3[k0];
    float m1 = sum2[k1] * (1.f / E_EDGES);
    float v1 = sumsq2[k1] * (1.f / E_EDGES) - m1 * m1;
    float s1 = rsqrtf(v1 + EPSBN) * gamma2[k1];
    float h1 = beta2[k1] - m1 * s1;
    float w31 = W3[k1];
    float b3v = b3[0];
    for (int j = gw; j < NDIS; j += nw) {
        float x0 = fmaxf(Z2[(size_t)j * H2 + k0] * s0 + h0, 0.f) * w30;
        float x1 = fmaxf(Z2[(size_t)j * H2 + k1] * s1 + h1, 0.f) * w31;
        float acc = x0 + x1;
        for (int off = 32; off > 0; off >>= 1)
            acc += __shfl_down(acc, off, 64);
        if (lane == 0) S[j] = 1.f / (1.f + expf(-(acc + b3v)));
    }
}

// ---------------- out[e] = S[dst[e]]  (int4/float4) ----------------
__global__ void k_out(const int* __restrict__ dst, const float* __restrict__ S,
                      float* __restrict__ out) {
    int e4 = blockIdx.x * blockDim.x + threadIdx.x;
    if (e4 < E4N) {
        int4 d = ((const int4*)dst)[e4];
        float4 o;
        o.x = S[d.x]; o.y = S[d.y]; o.z = S[d.z]; o.w = S[d.w];
        ((float4*)out)[e4] = o;
    }
}

extern "C" void kernel_launch(void* const* d_in, const int* in_sizes, int n_in,
                              void* d_out, int out_size, void* d_ws, size_t ws_size,
                              hipStream_t stream) {
    const float* h_drug    = (const float*)d_in[0];
    // d_in[1] = d_disease: unused (diseases only receive; drugs' GCN output is b_gcn)
    const float* W_gcn     = (const float*)d_in[2];
    const float* b_gcn     = (const float*)d_in[3];
    const float* W1        = (const float*)d_in[4];
    const float* b1        = (const float*)d_in[5];
    const float* gamma1    = (const float*)d_in[6];
    const float* beta1     = (const float*)d_in[7];
    const float* W2        = (const float*)d_in[8];
    const float* b2        = (const float*)d_in[9];
    const float* gamma2    = (const float*)d_in[10];
    const float* beta2     = (const float*)d_in[11];
    const float* W3        = (const float*)d_in[12];
    const float* b3        = (const float*)d_in[13];
    const int*   src       = (const int*)d_in[14];
    const int*   dst       = (const int*)d_in[15];
    float* out = (float*)d_out;

    // ---- workspace: zero-region first (k_pre), then uninitialized scratch ----
    char* ws = (char*)d_ws;
    int*   cnts    = (int*)ws;                       // 32*ND
    int*   cntd    = cnts + NCOPY * ND;              // 32*NDIS (becomes copyoff)
    float* sum1    = (float*)(cntd + NCOPY * NDIS);  // 256
    float* sumsq1  = sum1 + H1;                      // 256
    float* sum2    = sumsq1 + H1;                    // 128
    float* sumsq2  = sum2 + H2;                      // 128
    float* zero_end = sumsq2 + H2;

    int*   cnt_dst  = (int*)zero_end;                // NDIS
    float* norm_out = (float*)(cnt_dst + NDIS);      // ND
    int*   rank     = (int*)(norm_out + ND);         // E
    int*   ell_src  = rank + E_EDGES;                // NDIS*ELLS
    __half* M1h     = (__half*)(ell_src + NDIS * ELLS); // 128*256 fp16 (64 KB)
    __half* W2h     = M1h + DIM * H1;                // 256*128 fp16 (64 KB)
    float* c1v      = (float*)(W2h + D2 * H2);       // 256
    __half* hn      = (__half*)(c1v + H1);           // ND*128 fp16 (2.56 MB)
    float* Z1       = (float*)(hn + (size_t)ND * DIM); // NDIS*256
    float* Z2       = Z1 + (size_t)NDIS * H1;        // NDIS*128
    float* S        = Z2 + (size_t)NDIS * H2;        // NDIS

    k_pre<<<ZBLK + DIM + 1 + W2B, 256, 0, stream>>>((int4*)d_ws, W_gcn, W1, b_gcn, b1,
                                                    W2, M1h, c1v, W2h);
    k_degrees<<<(E4N + 255) / 256, 256, 0, stream>>>(src, dst, cnts, cntd, rank);
    k_red<<<(NDIS + 255) / 256, 256, 0, stream>>>(cnts, cntd, cnt_dst, norm_out);
    k_fill<<<FILLB + HNB, 256, 0, stream>>>(src, dst, rank, cntd, ell_src,
                                            norm_out, h_drug, hn);
    k_aggz1<<<WSGRID, 512, 0, stream>>>(ell_src, cnt_dst, hn, M1h, c1v, Z1, sum1, sumsq1);
    k_z2w<<<WSGRID, 512, 0, stream>>>(Z1, cnt_dst, sum1, sumsq1, gamma1, beta1,
                                      W2h, b2, Z2, sum2, sumsq2);
    k_score<<<512, 256, 0, stream>>>(Z2, sum2, sumsq2, gamma2, beta2, W3, b3, S);
    k_out<<<(E4N + 255) / 256, 256, 0, stream>>>(dst, S, out);
}

// Round 20
// 124.393 us; speedup vs baseline: 1.1260x; 1.1260x over previous
//
#include <hip/hip_runtime.h>
#include <hip/hip_fp16.h>

#define ND      10000
#define NDIS    10000
#define E_EDGES 400000
#define E4N     (E_EDGES / 4)
#define DIM     128
#define D2      256   // 2*DIM
#define H1      256   // d4/2
#define H2      128   // d4/4
#define EPSBN   1e-5f
#define GJ      8     // diseases per group (= waves per block)
#define NGRP    (NDIS / GJ)   // 1250
#define WSGRID  512
#define NCOPY   32    // privatized histogram copies
#define ELLS    128   // ELL row stride (max degree bound; Poisson(40) -> safe)
#define LDAH    132   // padded LDS row stride (halves): 66 dw = 33 b64-units, odd -> conflict-free
#define LDXH    260   // padded LDS row stride (halves): 65 b64-units, odd -> conflict-free
// zero region: NCOPY*(ND+NDIS) ints + 768 stat floats
#define ZERO_N4 ((NCOPY * (ND + NDIS) + 768) / 4)
#define ZBLK    ((ZERO_N4 + 255) / 256)
#define W2B     (D2 * H2 / 256)               // 128 W2->fp16 blocks in k_pre
#define FILLB   ((E_EDGES / 4 + 255) / 256)   // 391 edge blocks in k_fill
#define HNB     (ND * 32 / 256)               // 1250 hn-conversion blocks in k_fill

typedef _Float16 f16x8 __attribute__((ext_vector_type(8)));
typedef float    f32x4 __attribute__((ext_vector_type(4)));

// ------- fused: zero histograms/stats + M1h (fp16) / c1 precompute + W2->fp16 ------------
__global__ void k_pre(int4* __restrict__ zp,
                      const float* __restrict__ Wg, const float* __restrict__ W1,
                      const float* __restrict__ b_gcn, const float* __restrict__ b1,
                      const float* __restrict__ W2,
                      __half* __restrict__ M1h, float* __restrict__ c1,
                      __half* __restrict__ W2h) {
    int b = blockIdx.x;
    int t = threadIdx.x;
    if (b < ZBLK) {
        int i = b * 256 + t;
        if (i < ZERO_N4) zp[i] = make_int4(0, 0, 0, 0);
        return;
    }
    int r = b - ZBLK;          // 0..128+W2B
    if (r < DIM) {             // M1[r][t] = sum_c Wg[r][c] * W1[256+c][t]  -> fp16
        float acc = 0.f;
        #pragma unroll 8
        for (int c = 0; c < D2; ++c)
            acc += Wg[r * D2 + c] * W1[(D2 + c) * H1 + t];
        M1h[r * H1 + t] = __float2half_rn(acc);
    } else if (r == DIM) {     // c1[t]
        float acc = b1[t];
        #pragma unroll 4
        for (int i = 0; i < D2; ++i)
            acc += b_gcn[i] * (W1[i * H1 + t] + W1[(D2 + i) * H1 + t]);
        c1[t] = acc;
    } else {                   // W2 -> fp16
        int i = (r - DIM - 1) * 256 + t;
        W2h[i] = __float2half_rn(W2[i]);
    }
}

// ---------------- degree counting, 32-way privatized; dst-atomic returns edge rank -------
__global__ void k_degrees(const int* __restrict__ src, const int* __restrict__ dst,
                          int* __restrict__ cnts, int* __restrict__ cntd,
                          int* __restrict__ rank) {
    int e4 = blockIdx.x * blockDim.x + threadIdx.x;
    if (e4 >= E4N) return;
    int c = blockIdx.x & (NCOPY - 1);
    int4 sv = ((const int4*)src)[e4];
    int4 dv = ((const int4*)dst)[e4];
    atomicAdd(&cnts[c * ND + sv.x], 1);
    atomicAdd(&cnts[c * ND + sv.y], 1);
    atomicAdd(&cnts[c * ND + sv.z], 1);
    atomicAdd(&cnts[c * ND + sv.w], 1);
    int4 rv;
    rv.x = atomicAdd(&cntd[c * NDIS + dv.x], 1);
    rv.y = atomicAdd(&cntd[c * NDIS + dv.y], 1);
    rv.z = atomicAdd(&cntd[c * NDIS + dv.z], 1);
    rv.w = atomicAdd(&cntd[c * NDIS + dv.w], 1);
    ((int4*)rank)[e4] = rv;
}

// ------- reduce copies: totals, in-place per-copy exclusive prefix, norm_out -------------
__global__ void k_red(int* __restrict__ cnts, int* __restrict__ cntd,
                      int* __restrict__ cnt_dst, float* __restrict__ norm_out) {
    int d = blockIdx.x * blockDim.x + threadIdx.x;
    if (d >= NDIS) return;
    int s = 0;
    #pragma unroll
    for (int c = 0; c < NCOPY; ++c) {
        int v = cntd[c * NDIS + d];
        cntd[c * NDIS + d] = s;       // overwrite with exclusive prefix (copyoff)
        s += v;
    }
    cnt_dst[d] = s;
    int s2 = 0;
    #pragma unroll
    for (int c = 0; c < NCOPY; ++c) s2 += cnts[c * ND + d];
    norm_out[d] = rsqrtf(fmaxf((float)s2, 1.f));
}

// ------- ELL fill (atomic-free) + hn = fp16(norm_out * h_drug) pre-scale ----------------
__global__ void k_fill(const int* __restrict__ src, const int* __restrict__ dst,
                       const int* __restrict__ rank, const int* __restrict__ copyoff,
                       int* __restrict__ ell_src,
                       const float* __restrict__ norm_out, const float* __restrict__ h_drug,
                       __half* __restrict__ hn) {
    int b = blockIdx.x;
    if (b >= FILLB) {   // hn conversion: 8 rows per block, lane covers 4 cols (8B store)
        int row = (b - FILLB) * 8 + (threadIdx.x >> 5);
        int L = threadIdx.x & 31;
        float no = norm_out[row];
        float4 v = *(const float4*)&h_drug[(size_t)row * DIM + L * 4];
        __half2 h01 = __halves2half2(__float2half_rn(v.x * no), __float2half_rn(v.y * no));
        __half2 h23 = __halves2half2(__float2half_rn(v.z * no), __float2half_rn(v.w * no));
        uint2 u;
        u.x = *(unsigned int*)&h01;
        u.y = *(unsigned int*)&h23;
        *(uint2*)&hn[(size_t)row * DIM + L * 4] = u;
        return;
    }
    int e4 = b * blockDim.x + threadIdx.x;
    if (e4 >= E4N) return;
    int c = b & (NCOPY - 1);          // must match k_degrees' mapping
    int4 sv = ((const int4*)src)[e4];
    int4 dv = ((const int4*)dst)[e4];
    int4 rv = ((const int4*)rank)[e4];
    int ix = copyoff[c * NDIS + dv.x] + rv.x;
    int iy = copyoff[c * NDIS + dv.y] + rv.y;
    int iz = copyoff[c * NDIS + dv.z] + rv.z;
    int iw = copyoff[c * NDIS + dv.w] + rv.w;
    if (ix < ELLS) ell_src[(dv.x << 7) + ix] = sv.x;
    if (iy < ELLS) ell_src[(dv.y << 7) + iy] = sv.y;
    if (iz < ELLS) ell_src[(dv.z << 7) + iz] = sv.z;
    if (iw < ELLS) ell_src[(dv.w << 7) + iw] = sv.w;
}

// ===== FUSED aggregation + MFMA Z1 GEMM + weighted BN1 stats (R17-proven) =====
__global__ __launch_bounds__(512) void k_aggz1(
        const int* __restrict__ ell_src, const int* __restrict__ cnt_dst,
        const __half* __restrict__ hn, const __half* __restrict__ M1h,
        const float* __restrict__ c1,
        float* __restrict__ Z1, float* __restrict__ sum1, float* __restrict__ sumsq1) {
    __shared__ __half sA[16][LDAH];
    int tid = threadIdx.x;
    int wid = tid >> 6;                    // 0..7
    int lane = tid & 63;
    int hf = lane >> 5, L = lane & 31;     // phase-A roles
    int l15 = lane & 15, lg = lane >> 4;   // MFMA roles

    for (int x = tid; x < 8 * LDAH; x += 512)   // zero pad rows 8..15
        sA[8 + x / LDAH][x % LDAH] = __float2half(0.f);

    const _Float16* M1f = (const _Float16*)M1h;
    int c0a = 32 * wid + l15;
    int c0b = c0a + 16;
    f16x8 bfr[2][4];
    #pragma unroll
    for (int t = 0; t < 2; ++t) {
        int cc = t ? c0b : c0a;
        #pragma unroll
        for (int kk = 0; kk < 4; ++kk) {
            f16x8 f;
            #pragma unroll
            for (int j = 0; j < 4; ++j) {
                f[j]     = M1f[(kk * 32 + 4 * lg + j) * H1 + cc];
                f[j + 4] = M1f[(kk * 32 + 16 + 4 * lg + j) * H1 + cc];
            }
            bfr[t][kk] = f;
        }
    }
    float c1a = c1[c0a], c1b = c1[c0b];
    float psA = 0.f, pqA = 0.f, psB = 0.f, pqB = 0.f;

    for (int grp = blockIdx.x; grp < NGRP; grp += gridDim.x) {
        int jb = grp * GJ;
        // ---- phase A: gather disease jb+wid into sA[wid] (fp16) ----
        {
            int j = jb + wid;
            int n = cnt_dst[j];
            int nn = n < ELLS ? n : ELLS;
            int beg = j << 7;
            float4 acc = make_float4(0.f, 0.f, 0.f, 0.f);
            float4 acc2 = make_float4(0.f, 0.f, 0.f, 0.f);
            int i = hf;
            for (; i + 2 < nn; i += 4) {   // two independent chains per half-wave
                int s0 = ell_src[beg + i];
                int s1 = ell_src[beg + i + 2];
                uint2 u0 = *(const uint2*)&hn[(size_t)s0 * DIM + L * 4];
                uint2 u1 = *(const uint2*)&hn[(size_t)s1 * DIM + L * 4];
                float2 a01 = __half22float2(*(__half2*)&u0.x);
                float2 a23 = __half22float2(*(__half2*)&u0.y);
                float2 b01 = __half22float2(*(__half2*)&u1.x);
                float2 b23 = __half22float2(*(__half2*)&u1.y);
                acc.x += a01.x; acc.y += a01.y; acc.z += a23.x; acc.w += a23.y;
                acc2.x += b01.x; acc2.y += b01.y; acc2.z += b23.x; acc2.w += b23.y;
            }
            for (; i < nn; i += 2) {
                int s0 = ell_src[beg + i];
                uint2 u0 = *(const uint2*)&hn[(size_t)s0 * DIM + L * 4];
                float2 a01 = __half22float2(*(__half2*)&u0.x);
                float2 a23 = __half22float2(*(__half2*)&u0.y);
                acc.x += a01.x; acc.y += a01.y; acc.z += a23.x; acc.w += a23.y;
            }
            acc.x += acc2.x; acc.y += acc2.y; acc.z += acc2.z; acc.w += acc2.w;
            acc.x += __shfl_down(acc.x, 32, 64);
            acc.y += __shfl_down(acc.y, 32, 64);
            acc.z += __shfl_down(acc.z, 32, 64);
            acc.w += __shfl_down(acc.w, 32, 64);
            if (hf == 0) {
                float ni = rsqrtf(fmaxf((float)n, 1.f));
                __half2 h01 = __halves2half2(__float2half_rn(acc.x * ni),
                                             __float2half_rn(acc.y * ni));
                __half2 h23 = __halves2half2(__float2half_rn(acc.z * ni),
                                             __float2half_rn(acc.w * ni));
                uint2 u;
                u.x = *(unsigned int*)&h01;
                u.y = *(unsigned int*)&h23;
                *(uint2*)&sA[wid][L * 4] = u;
            }
        }
        __syncthreads();
        // ---- phase B: MFMA.  A-frag: row=l15, k-split {4lg+j} u {16+4lg+j} ----
        {
            f32x4 cA = {0.f, 0.f, 0.f, 0.f};
            f32x4 cB = {0.f, 0.f, 0.f, 0.f};
            const _Float16* arow = (const _Float16*)&sA[l15][0];
            #pragma unroll
            for (int kk = 0; kk < 4; ++kk) {
                uint2 lo = *(const uint2*)&arow[kk * 32 + 4 * lg];
                uint2 hi = *(const uint2*)&arow[kk * 32 + 16 + 4 * lg];
                f16x8 af;
                ((uint2*)&af)[0] = lo;
                ((uint2*)&af)[1] = hi;
                cA = __builtin_amdgcn_mfma_f32_16x16x32_f16(af, bfr[0][kk], cA, 0, 0, 0);
                cB = __builtin_amdgcn_mfma_f32_16x16x32_f16(af, bfr[1][kk], cB, 0, 0, 0);
            }
            int row0 = lg * 4;             // C rows: row0..row0+3 ; only rows <8 are real
            if (row0 < 8) {
                #pragma unroll
                for (int reg = 0; reg < 4; ++reg) {
                    int row = row0 + reg;
                    float w = (float)cnt_dst[jb + row];
                    float za = cA[reg] + c1a;
                    float zb = cB[reg] + c1b;
                    Z1[(size_t)(jb + row) * H1 + c0a] = za;
                    Z1[(size_t)(jb + row) * H1 + c0b] = zb;
                    psA += w * za; pqA += w * za * za;
                    psB += w * zb; pqB += w * zb * zb;
                }
            }
        }
        __syncthreads();
    }
    psA += __shfl_down(psA, 16, 64);
    pqA += __shfl_down(pqA, 16, 64);
    psB += __shfl_down(psB, 16, 64);
    pqB += __shfl_down(pqB, 16, 64);
    if (lane < 16) {
        atomicAdd(&sum1[32 * wid + lane], psA);
        atomicAdd(&sumsq1[32 * wid + lane], pqA);
        atomicAdd(&sum1[32 * wid + 16 + lane], psB);
        atomicAdd(&sumsq1[32 * wid + 16 + lane], pqB);
    }
}

// ===== Z2 = relu(bn1(Z1)) @ W2 + b2 ; BN2 stats — MFMA (R17-proven) =====
__global__ __launch_bounds__(512) void k_z2w(
        const float* __restrict__ Z1, const int* __restrict__ cnt_dst,
        const float* __restrict__ sum1, const float* __restrict__ sumsq1,
        const float* __restrict__ gamma1, const float* __restrict__ beta1,
        const __half* __restrict__ W2h, const float* __restrict__ b2,
        float* __restrict__ Z2, float* __restrict__ sum2, float* __restrict__ sumsq2) {
    __shared__ __half sX[16][LDXH];
    __shared__ float sc1[H1], sh1[H1];     // 2 KB
    int tid = threadIdx.x;
    int wid = tid >> 6;
    int lane = tid & 63;
    int l15 = lane & 15, lg = lane >> 4;

    for (int x = tid; x < 8 * LDXH; x += 512)   // zero pad rows 8..15
        sX[8 + x / LDXH][x % LDXH] = __float2half(0.f);

    const _Float16* W2f = (const _Float16*)W2h;
    int cc = 16 * wid + l15;               // this lane's output column
    f16x8 bfr[8];
    #pragma unroll
    for (int kk = 0; kk < 8; ++kk) {
        f16x8 f;
        #pragma unroll
        for (int j = 0; j < 4; ++j) {
            f[j]     = W2f[(kk * 32 + 4 * lg + j) * H2 + cc];
            f[j + 4] = W2f[(kk * 32 + 16 + 4 * lg + j) * H2 + cc];
        }
        bfr[kk] = f;
    }
    if (tid < H1) {   // inline BN1 finalize
        float mn = sum1[tid] * (1.f / E_EDGES);
        float vv = sumsq1[tid] * (1.f / E_EDGES) - mn * mn;
        float s = rsqrtf(vv + EPSBN) * gamma1[tid];
        sc1[tid] = s;
        sh1[tid] = beta1[tid] - mn * s;
    }
    float b2c = b2[cc];
    float ps = 0.f, pq = 0.f;
    __syncthreads();
    for (int grp = blockIdx.x; grp < NGRP; grp += gridDim.x) {
        int jb = grp * GJ;
        {   // stage: rows 0-7 = fp16 relu(bn1(Z1[jb..jb+7]))  (512 thr x 4 elems)
            int g = tid >> 6;
            int c = (tid * 4) & (H1 - 1);
            float4 v = ((const float4*)(Z1 + (size_t)jb * H1))[tid];
            v.x = fmaxf(v.x * sc1[c]     + sh1[c],     0.f);
            v.y = fmaxf(v.y * sc1[c + 1] + sh1[c + 1], 0.f);
            v.z = fmaxf(v.z * sc1[c + 2] + sh1[c + 2], 0.f);
            v.w = fmaxf(v.w * sc1[c + 3] + sh1[c + 3], 0.f);
            __half2 h01 = __halves2half2(__float2half_rn(v.x), __float2half_rn(v.y));
            __half2 h23 = __halves2half2(__float2half_rn(v.z), __float2half_rn(v.w));
            uint2 u;
            u.x = *(unsigned int*)&h01;
            u.y = *(unsigned int*)&h23;
            *(uint2*)&sX[g][c] = u;
        }
        __syncthreads();
        {   // MFMA: D[16x128] = X[16x256] @ W2h
            f32x4 cacc = {0.f, 0.f, 0.f, 0.f};
            const _Float16* arow = (const _Float16*)&sX[l15][0];
            #pragma unroll
            for (int kk = 0; kk < 8; ++kk) {
                uint2 lo = *(const uint2*)&arow[kk * 32 + 4 * lg];
                uint2 hi = *(const uint2*)&arow[kk * 32 + 16 + 4 * lg];
                f16x8 af;
                ((uint2*)&af)[0] = lo;
                ((uint2*)&af)[1] = hi;
                cacc = __builtin_amdgcn_mfma_f32_16x16x32_f16(af, bfr[kk], cacc, 0, 0, 0);
            }
            int row0 = lg * 4;
            if (row0 < 8) {
                #pragma unroll
                for (int reg = 0; reg < 4; ++reg) {
                    int row = row0 + reg;
                    float w = (float)cnt_dst[jb + row];
                    float z = cacc[reg] + b2c;
                    Z2[(size_t)(jb + row) * H2 + cc] = z;
                    ps += w * z;
                    pq += w * z * z;
                }
            }
        }
        __syncthreads();
    }
    ps += __shfl_down(ps, 16, 64);
    pq += __shfl_down(pq, 16, 64);
    if (lane < 16) {
        atomicAdd(&sum2[cc], ps);
        atomicAdd(&sumsq2[cc], pq);
    }
}

// ------- S[j] = sigmoid( relu(bn2(Z2[j])) @ W3 + b3 )  (BN2 hoisted, grid-stride) --------
__global__ void k_score(const float* __restrict__ Z2,
                        const float* __restrict__ sum2, const float* __restrict__ sumsq2,
                        const float* __restrict__ gamma2, const float* __restrict__ beta2,
                        const float* __restrict__ W3, const float* __restrict__ b3,
                        float* __restrict__ S) {
    int lane = threadIdx.x & 63;
    int gw = (blockIdx.x * blockDim.x + threadIdx.x) >> 6;
    int nw = (gridDim.x * blockDim.x) >> 6;
    int k0 = lane, k1 = lane + 64;
    float m0 = sum2[k0] * (1.f / E_EDGES);
    float v0 = sumsq2[k0] * (1.f / E_EDGES) - m0 * m0;
    float s0 = rsqrtf(v0 + EPSBN) * gamma2[k0];
    float h0 = beta2[k0] - m0 * s0;
    float w30 = W3[k0];
    float m1 = sum2[k1] * (1.f / E_EDGES);
    float v1 = sumsq2[k1] * (1.f / E_EDGES) - m1 * m1;
    float s1 = rsqrtf(v1 + EPSBN) * gamma2[k1];
    float h1 = beta2[k1] - m1 * s1;
    float w31 = W3[k1];
    float b3v = b3[0];
    for (int j = gw; j < NDIS; j += nw) {
        float x0 = fmaxf(Z2[(size_t)j * H2 + k0] * s0 + h0, 0.f) * w30;
        float x1 = fmaxf(Z2[(size_t)j * H2 + k1] * s1 + h1, 0.f) * w31;
        float acc = x0 + x1;
        for (int off = 32; off > 0; off >>= 1)
            acc += __shfl_down(acc, off, 64);
        if (lane == 0) S[j] = 1.f / (1.f + expf(-(acc + b3v)));
    }
}

// ---------------- out[e] = S[dst[e]]  (int4/float4) ----------------
__global__ void k_out(const int* __restrict__ dst, const float* __restrict__ S,
                      float* __restrict__ out) {
    int e4 = blockIdx.x * blockDim.x + threadIdx.x;
    if (e4 < E4N) {
        int4 d = ((const int4*)dst)[e4];
        float4 o;
        o.x = S[d.x]; o.y = S[d.y]; o.z = S[d.z]; o.w = S[d.w];
        ((float4*)out)[e4] = o;
    }
}

extern "C" void kernel_launch(void* const* d_in, const int* in_sizes, int n_in,
                              void* d_out, int out_size, void* d_ws, size_t ws_size,
                              hipStream_t stream) {
    const float* h_drug    = (const float*)d_in[0];
    // d_in[1] = d_disease: unused (diseases only receive; drugs' GCN output is b_gcn)
    const float* W_gcn     = (const float*)d_in[2];
    const float* b_gcn     = (const float*)d_in[3];
    const float* W1        = (const float*)d_in[4];
    const float* b1        = (const float*)d_in[5];
    const float* gamma1    = (const float*)d_in[6];
    const float* beta1     = (const float*)d_in[7];
    const float* W2        = (const float*)d_in[8];
    const float* b2        = (const float*)d_in[9];
    const float* gamma2    = (const float*)d_in[10];
    const float* beta2     = (const float*)d_in[11];
    const float* W3        = (const float*)d_in[12];
    const float* b3        = (const float*)d_in[13];
    const int*   src       = (const int*)d_in[14];
    const int*   dst       = (const int*)d_in[15];
    float* out = (float*)d_out;

    // ---- workspace: zero-region first (k_pre), then uninitialized scratch ----
    char* ws = (char*)d_ws;
    int*   cnts    = (int*)ws;                       // 32*ND
    int*   cntd    = cnts + NCOPY * ND;              // 32*NDIS (becomes copyoff)
    float* sum1    = (float*)(cntd + NCOPY * NDIS);  // 256
    float* sumsq1  = sum1 + H1;                      // 256
    float* sum2    = sumsq1 + H1;                    // 128
    float* sumsq2  = sum2 + H2;                      // 128
    float* zero_end = sumsq2 + H2;

    int*   cnt_dst  = (int*)zero_end;                // NDIS
    float* norm_out = (float*)(cnt_dst + NDIS);      // ND
    int*   rank     = (int*)(norm_out + ND);         // E
    int*   ell_src  = rank + E_EDGES;                // NDIS*ELLS
    __half* M1h     = (__half*)(ell_src + NDIS * ELLS); // 128*256 fp16 (64 KB)
    __half* W2h     = M1h + DIM * H1;                // 256*128 fp16 (64 KB)
    float* c1v      = (float*)(W2h + D2 * H2);       // 256
    __half* hn      = (__half*)(c1v + H1);           // ND*128 fp16 (2.56 MB)
    float* Z1       = (float*)(hn + (size_t)ND * DIM); // NDIS*256
    float* Z2       = Z1 + (size_t)NDIS * H1;        // NDIS*128
    float* S        = Z2 + (size_t)NDIS * H2;        // NDIS

    k_pre<<<ZBLK + DIM + 1 + W2B, 256, 0, stream>>>((int4*)d_ws, W_gcn, W1, b_gcn, b1,
                                                    W2, M1h, c1v, W2h);
    k_degrees<<<(E4N + 255) / 256, 256, 0, stream>>>(src, dst, cnts, cntd, rank);
    k_red<<<(NDIS + 255) / 256, 256, 0, stream>>>(cnts, cntd, cnt_dst, norm_out);
    k_fill<<<FILLB + HNB, 256, 0, stream>>>(src, dst, rank, cntd, ell_src,
                                            norm_out, h_drug, hn);
    k_aggz1<<<WSGRID, 512, 0, stream>>>(ell_src, cnt_dst, hn, M1h, c1v, Z1, sum1, sumsq1);
    k_z2w<<<WSGRID, 512, 0, stream>>>(Z1, cnt_dst, sum1, sumsq1, gamma1, beta1,
                                      W2h, b2, Z2, sum2, sumsq2);
    k_score<<<512, 256, 0, stream>>>(Z2, sum2, sumsq2, gamma2, beta2, W3, b3, S);
    k_out<<<(E4N + 255) / 256, 256, 0, stream>>>(dst, S, out);
}